// Round 2
// baseline (196.173 us; speedup 1.0000x reference)
//
#include <hip/hip_runtime.h>

typedef unsigned long long u64;

#define G 512
#define T 128
#define P 256
#define B 512

struct __align__(16) U64x2 { u64 x, y; };

// ---------------------------------------------------------------------------
// Pack param_vals (B x P fp32 of 0/1) into B x 4 u64 bitmasks.
// Bit layout: word j (j=0..3), bit L  <->  p = 4*L + j. Same permutation is
// applied to the matrices, so parity of AND is preserved.
// ---------------------------------------------------------------------------
__global__ __launch_bounds__(256) void pack_pv_kernel(
    const float* __restrict__ pv, u64* __restrict__ out)
{
    int lane = threadIdx.x & 63;
    int wave = threadIdx.x >> 6;
    int row  = blockIdx.x * 4 + wave;   // 128 blocks * 4 waves = 512 rows
    const float4* src = (const float4*)(pv + (size_t)row * P);
    float4 f = src[lane];
    u64 w0 = __ballot(f.x != 0.0f);
    u64 w1 = __ballot(f.y != 0.0f);
    u64 w2 = __ballot(f.z != 0.0f);
    u64 w3 = __ballot(f.w != 0.0f);
    if (lane == 0) {
        U64x2* d = (U64x2*)(out + row * 4);
        U64x2 a; a.x = w0; a.y = w1;
        U64x2 c; c.x = w2; c.y = w3;
        d[0] = a;
        d[1] = c;
    }
}

// ---------------------------------------------------------------------------
// Pack psi_const / phi_const into per-graph bitwords:
//   codes[g*4 + 0,1] = psi const bits for t in [0,64), [64,128)
//   codes[g*4 + 2,3] = phi const bits
// ---------------------------------------------------------------------------
__global__ __launch_bounds__(256) void pack_codes_kernel(
    const int* __restrict__ psi_c, const int* __restrict__ phi_c,
    u64* __restrict__ codes)
{
    int lane = threadIdx.x & 63;
    int wave = threadIdx.x >> 6;
    int g = blockIdx.x * 4 + wave;      // 128 blocks * 4 waves = 512 graphs
    u64 a0 = __ballot(psi_c[g * T + lane]      != 0);
    u64 a1 = __ballot(psi_c[g * T + 64 + lane] != 0);
    u64 b0 = __ballot(phi_c[g * T + lane]      != 0);
    u64 b1 = __ballot(phi_c[g * T + 64 + lane] != 0);
    if (lane == 0) {
        U64x2* d = (U64x2*)(codes + g * 4);
        U64x2 x; x.x = a0; x.y = a1;
        U64x2 y; y.x = b0; y.y = b1;
        d[0] = x;
        d[1] = y;
    }
}

// ---------------------------------------------------------------------------
// Pack both fp32 matrices into bitmask rows in global memory:
//   rows[(g*T + t)*8 + 0..3] = psi words, + 4..7 = phi words  (64 B per (g,t))
// Pure memory-bound streaming kernel: 128 MiB read, 4 MiB written.
// ---------------------------------------------------------------------------
__global__ __launch_bounds__(256) void pack_mat_kernel(
    const float* __restrict__ psi, const float* __restrict__ phi,
    u64* __restrict__ rows)
{
    int lane = threadIdx.x & 63;
    int wave = threadIdx.x >> 6;
    int wid  = blockIdx.x * 4 + wave;   // 2048 blocks * 4 waves = 8192 waves
    #pragma unroll 4
    for (int j = 0; j < 16; ++j) {
        int item = wid * 16 + j;        // 0 .. 131071
        int m = item >> 16;             // 0 = psi, 1 = phi
        int r = item & 65535;           // g*T + t
        const float* mat = m ? phi : psi;
        const float4* src = (const float4*)(mat + (size_t)r * P);
        float4 f = src[lane];
        u64 w0 = __ballot(f.x != 0.0f);
        u64 w1 = __ballot(f.y != 0.0f);
        u64 w2 = __ballot(f.z != 0.0f);
        u64 w3 = __ballot(f.w != 0.0f);
        if (lane == 0) {
            U64x2* d = (U64x2*)(rows + (size_t)r * 8 + m * 4);
            U64x2 a; a.x = w0; a.y = w1;
            U64x2 c; c.x = w2; c.y = w3;
            d[0] = a;
            d[1] = c;
        }
    }
}

// ---------------------------------------------------------------------------
// Main compute: no LDS. Row pointer is wave-uniform -> compiler emits scalar
// (s_load_dwordx16) loads; inner loop is VALU and/xor/popcount on v in VGPRs
// against row words in SGPRs. Const bits fold in on the scalar pipe.
// grid = G*2 blocks of 256 threads; thread owns one (b, g).
// ---------------------------------------------------------------------------
__global__ __launch_bounds__(256) void pi_main_kernel(
    const u64* __restrict__ rows,
    const u64* __restrict__ codes,
    const u64* __restrict__ pv,
    float4*    __restrict__ out)
{
    const int g = blockIdx.x >> 1;
    const int b = ((blockIdx.x & 1) << 8) | threadIdx.x;

    const u64* v = pv + (size_t)b * 4;
    u64 v0 = v[0], v1 = v[1], v2 = v[2], v3 = v[3];

    const u64* rp = rows + (size_t)g * (T * 8);

    unsigned e = 0;
    for (int blk = 0; blk < 2; ++blk) {
        u64 pcw = codes[g * 4 + blk];       // wave-uniform (scalar)
        u64 qcw = codes[g * 4 + 2 + blk];
        const u64* r = rp + blk * 64 * 8;
        #pragma unroll 4
        for (int i = 0; i < 64; ++i, r += 8) {
            u64 ma = (r[0] & v0) ^ (r[1] & v1) ^ (r[2] & v2) ^ (r[3] & v3);
            u64 mb = (r[4] & v0) ^ (r[5] & v1) ^ (r[6] & v2) ^ (r[7] & v3);
            unsigned pa = (unsigned)__popcll(ma) ^ (unsigned)(pcw >> i);
            unsigned pb = (unsigned)__popcll(mb) ^ (unsigned)(qcw >> i);
            e ^= pa & pb;                   // only bit 0 meaningful
        }
    }
    e &= 1u;

    float s = 1.0f - 2.0f * (float)e;       // (-1)^e
    out[(size_t)b * G + g] = make_float4(s, 0.0f, 0.0f, 0.0f);
}

extern "C" void kernel_launch(void* const* d_in, const int* in_sizes, int n_in,
                              void* d_out, int out_size, void* d_ws, size_t ws_size,
                              hipStream_t stream) {
    const int*   psi_const  = (const int*)  d_in[0];
    const float* psi_params = (const float*)d_in[1];
    const int*   phi_const  = (const int*)  d_in[2];
    const float* phi_params = (const float*)d_in[3];
    const float* param_vals = (const float*)d_in[4];

    // Workspace layout (u64 elements):
    //   rows : G*T*8      = 524288 u64 (4 MiB)
    //   codes: G*4        = 2048 u64  (16 KB)
    //   pv   : B*4        = 2048 u64  (16 KB)
    u64* ws    = (u64*)d_ws;
    u64* rows  = ws;
    u64* codes = ws + (size_t)G * T * 8;
    u64* pv    = codes + (size_t)G * 4;

    pack_pv_kernel   <<<B / 4, 256, 0, stream>>>(param_vals, pv);
    pack_codes_kernel<<<G / 4, 256, 0, stream>>>(psi_const, phi_const, codes);
    pack_mat_kernel  <<<2048,  256, 0, stream>>>(psi_params, phi_params, rows);
    pi_main_kernel   <<<G * 2, 256, 0, stream>>>(rows, codes, pv, (float4*)d_out);
}